// Round 5
// baseline (242.786 us; speedup 1.0000x reference)
//
#include <hip/hip_runtime.h>
#include <cstdint>
#include <cstddef>

// ---------------------------------------------------------------------------
// MultiHeadAttention forward, MI355X/gfx950.
// fused cvt+QKV GEMM (MFMA) -> flash attention -> fused cvt+out-proj.
// MFMA layouts (m89/m91/m120):
//   K=32 A-frag: lane l holds A[m=l&15][k=(l>>4)*8+j], j=0..7
//   K=32 B-frag: lane l holds Bt[n=l&15][k=(l>>4)*8+j]
//   K=16 A/B-frag: lane l holds X[.=l&15][k=(l>>4)*4+c], c=0..3
//   C/D: lane l, reg r holds D[m=(l>>4)*4+r][n=l&15]
// R12: eliminate the cvt7 pre-pass; revert R11's double-buffer.
// Evidence: R11 dbuf regressed (+9us) -> projection GEMMs are NOT
// serial-latency-bound (3 blocks/CU TLP already overlaps barrier stalls,
// m114). Across R8-R11, Dtotal tracks Dattn 1:1 and GEMM inner-loop changes
// land in noise -> non-attn time is cvt7 (~17us, 100MB pure conversion
// traffic + launch) and overheads, not MFMA throughput. So:
//  * qkv_gemm reads fp32 q/k/v/W directly; staging = float4 load -> cvt ->
//    ds_write_b64 (LDS layout unchanged, compute loop untouched). cvt7 and
//    the qb/kb/vb/w* workspace buffers are gone (ws 67->34MB, 4->3 launches,
//    -100MB HBM round-trip).
//  * oproj_gemm reg-stages fp32 Wo the same way; attn input stays bf16 via
//    async_cp16. Single-buffer (R10 structure) for both GEMMs.
// attn unchanged from R10 (62.1us: 4 waves x 32q sharing K/V LDS reads, XCD
// swizzle (FETCH 12.4MB), tree softmax, defer-max THR=8, exp2 domain with
// QSCALE folded into Q projection, no setprio).
// ---------------------------------------------------------------------------

#define D_MODEL 1024
#define NHEAD   16
#define HDIM    64
#define BATCH   2
#define SEQ     2048
#define BT      (BATCH * SEQ)   // 4096

// (1/sqrt(HDIM)) * log2(e) -- folds softmax scale + exp->exp2 conversion
#define QSCALE 0.18033688011112043f

typedef __bf16 bf16;
typedef __bf16 bf16x8 __attribute__((ext_vector_type(8)));
typedef __bf16 bf16x4 __attribute__((ext_vector_type(4)));
typedef float  floatx4 __attribute__((ext_vector_type(4)));
typedef short  short4v __attribute__((ext_vector_type(4)));

#define MFMA16(a, b, c) __builtin_amdgcn_mfma_f32_16x16x32_bf16((a), (b), (c), 0, 0, 0)

__device__ __forceinline__ floatx4 MFMA16B(bf16x4 a, bf16x4 b, floatx4 c) {
  return __builtin_amdgcn_mfma_f32_16x16x16bf16_1k(
      __builtin_bit_cast(short4v, a), __builtin_bit_cast(short4v, b), c, 0, 0, 0);
}

__device__ __forceinline__ float fexp2(float x) {
  return __builtin_amdgcn_exp2f(x);   // v_exp_f32: D = 2^S0
}

// async global->LDS, 16B per lane. LDS dest = wave-uniform base + lane*16.
__device__ __forceinline__ void async_cp16(const bf16* g, bf16* l) {
  __builtin_amdgcn_global_load_lds(
      (__attribute__((address_space(1))) void*)(g),
      (__attribute__((address_space(3))) void*)(l), 16, 0, 0);
}

__device__ __forceinline__ bf16x4 cvt4(float4 f) {
  bf16x4 h;
  h[0] = (bf16)f.x; h[1] = (bf16)f.y; h[2] = (bf16)f.z; h[3] = (bf16)f.w;
  return h;
}

// ---------------------------------------------------------------------------
// 128x128-tile GEMM core, K=1024, BK=32, fp32 inputs converted during
// staging (single-buffered, R10 structure: TLP across 3 blocks/CU hides the
// staging latency; R11 proved explicit dbuf is a net loss here).
// Staging: thread t covers (row = ii*32 + t>>3, ci = t&7): one float4 of A
// and one of W per ii, cvt to bf16x4, ds_write_b64. LDS layout [row][32]
// identical to the bf16 version, so the MFMA loop is unchanged.
// ---------------------------------------------------------------------------
__device__ __forceinline__ void gemm128_core_f32(
    const float* __restrict__ A, const float* __restrict__ W,
    int m0, int n0, bf16* As, bf16* Bs, floatx4 acc[4][4])
{
  const int t = threadIdx.x;
  const int l = t & 63, w = t >> 6;
  const int quad = l >> 4, lr = l & 15;
  const int wm = (w >> 1) * 64, wn = (w & 1) * 64;
  const int srow = t >> 3, sci = t & 7;

  floatx4 z = {0.f, 0.f, 0.f, 0.f};
#pragma unroll
  for (int i = 0; i < 4; i++)
#pragma unroll
    for (int j = 0; j < 4; j++) acc[i][j] = z;

  for (int kt = 0; kt < 1024; kt += 32) {
    __syncthreads();   // all waves done reading As/Bs from previous step
#pragma unroll
    for (int ii = 0; ii < 4; ii++) {
      int row = ii * 32 + srow;
      float4 fa = *(const float4*)(A + (size_t)(m0 + row) * 1024 + kt + sci * 4);
      float4 fw = *(const float4*)(W + (size_t)(n0 + row) * 1024 + kt + sci * 4);
      *(bf16x4*)(As + row * 32 + sci * 4) = cvt4(fa);
      *(bf16x4*)(Bs + row * 32 + sci * 4) = cvt4(fw);
    }
    __syncthreads();   // ds_writes visible (lgkmcnt drain)

    bf16x8 af[4], bfr[4];
#pragma unroll
    for (int i = 0; i < 4; i++) {
      af[i]  = *(const bf16x8*)(As + (wm + i * 16 + lr) * 32 + quad * 8);
      bfr[i] = *(const bf16x8*)(Bs + (wn + i * 16 + lr) * 32 + quad * 8);
    }
#pragma unroll
    for (int i = 0; i < 4; i++)
#pragma unroll
      for (int j = 0; j < 4; j++)
        acc[i][j] = MFMA16(af[i], bfr[j], acc[i][j]);
  }
}

// ---------------------------------------------------------------------------
// Fused cvt+QKV projection. zid selects (q,Wq)->qh, (k,Wk)->kh, (v,Wv)->vt.
// Inputs fp32 (converted in staging). qh,kh: [B*H][T][64]; v stored
// TRANSPOSED [B*H][64][T]. qh pre-scaled by QSCALE (exp2-domain softmax).
// ---------------------------------------------------------------------------
__global__ __launch_bounds__(256) void qkv_gemm(
    const float* __restrict__ qb, const float* __restrict__ kb, const float* __restrict__ vb,
    const float* __restrict__ wq, const float* __restrict__ wk, const float* __restrict__ wv,
    const float* __restrict__ biasq, const float* __restrict__ biask, const float* __restrict__ biasv,
    bf16* __restrict__ qh, bf16* __restrict__ kh, bf16* __restrict__ vt)
{
  __shared__ bf16 As[128 * 32];   // 8KB
  __shared__ bf16 Bs[128 * 32];   // 8KB
  const int zid = blockIdx.z;
  const float* A = (zid == 0) ? qb : ((zid == 1) ? kb : vb);
  const float* W = (zid == 0) ? wq : ((zid == 1) ? wk : wv);
  const float* bias = (zid == 0) ? biasq : ((zid == 1) ? biask : biasv);
  const int m0 = blockIdx.x * 128, n0 = blockIdx.y * 128;

  floatx4 acc[4][4];
  gemm128_core_f32(A, W, m0, n0, As, Bs, acc);

  const int t = threadIdx.x, l = t & 63, w = t >> 6;
  const int quad = l >> 4, lr = l & 15;
  const int wm = (w >> 1) * 64, wn = (w & 1) * 64;
  const float sc = (zid == 0) ? QSCALE : 1.0f;

  if (zid < 2) {
    bf16* out = (zid == 0) ? qh : kh;
#pragma unroll
    for (int i = 0; i < 4; i++) {
      int mbase = m0 + wm + i * 16 + quad * 4;       // global row (b*2048+t)
      int b  = mbase >> 11;
      int tq = mbase & 2047;
#pragma unroll
      for (int j = 0; j < 4; j++) {
        int n = n0 + wn + j * 16 + lr;               // e = h*64 + dh
        float bv = bias[n];
        int h = n >> 6, dh = n & 63;
        bf16* p = out + ((size_t)((b * NHEAD + h) * SEQ + tq)) * HDIM + dh;
#pragma unroll
        for (int r = 0; r < 4; r++)
          p[(size_t)r * HDIM] = (bf16)((acc[i][j][r] + bv) * sc);
      }
    }
  } else {
#pragma unroll
    for (int i = 0; i < 4; i++) {
      int mbase = m0 + wm + i * 16 + quad * 4;
      int b  = mbase >> 11;
      int tq = mbase & 2047;
#pragma unroll
      for (int j = 0; j < 4; j++) {
        int n = n0 + wn + j * 16 + lr;
        float bv = bias[n];
        int h = n >> 6, dh = n & 63;
        bf16x4 pk;
#pragma unroll
        for (int r = 0; r < 4; r++) pk[r] = (bf16)(acc[i][j][r] + bv);
        *(bf16x4*)(vt + ((size_t)((b * NHEAD + h) * HDIM + dh)) * SEQ + tq) = pk;
      }
    }
  }
}

// ---------------------------------------------------------------------------
// Flash attention. Grid (T/128, B*H), block 256 = 4 waves; wave w owns
// q-rows qt0 + w*32 + {0..31} as TWO groups of 16 (g=0,1; q = g*16 + lr),
// all 128 keys of each tile. Every K-frag / V-frag LDS read feeds BOTH
// groups' MFMAs. Block ids are XCD-swizzled so the 16 q-tile blocks of a
// given bh (+3 more bh) share one XCD's L2 (K/V working set 3MB < 4MB).
// LDS (double-buffered, 2 x 32 KB):
//   K  [128 rows][64 el],  8-el chunk ci stored at physical ci ^ (row & 7)
//   V^T[ 64 rows][128 el], 8-el chunk ci stored at physical ci ^ (row & 15)
// Staged via global_load_lds: 4 waves x (4 K-seg + 4 V-seg) x 1 KB per tile;
// one barrier per tile (issue DMA for tile k+1 right after barrier k).
// Compute: S^T = MFMA16x16x32(K,Q) (lane q = lr) per group, per-group
// tree-reduced exp2 softmax with defer-max skip, in-register PV via
// MFMA16x16x16. No setprio (hurts barrier-locked waves, R9/m190).
// Epilogue: normalize, LDS transpose ([128][72] overlay), coalesced store.
// ---------------------------------------------------------------------------
__global__ __launch_bounds__(256, 2) void attn_fused(
    const bf16* __restrict__ qh, const bf16* __restrict__ kh,
    const bf16* __restrict__ vt, bf16* __restrict__ attn)
{
  __shared__ __align__(16) char smem[65536];   // 2 x (K 16KB + V 16KB)

  const int t = threadIdx.x, l = t & 63, w = t >> 6;   // w in 0..3
  const int quad = l >> 4, lr = l & 15;

  // XCD swizzle: hardware dispatch round-robins linear block id across the
  // 8 XCDs (id % 8 = XCD). Give XCD x the 4 heads {x, x+8, x+16, x+24},
  // all 16 q-tiles each: bijective over the 512-block grid.
  const int hb  = blockIdx.y * 16 + blockIdx.x;   // dispatch-linear id
  const int j   = hb >> 3;
  const int bh  = (hb & 7) + ((j & 3) << 3);
  const int qt0 = (j >> 2) * 128;

  const bf16* qg = qh + (size_t)bh * SEQ * HDIM;
  const bf16* kg = kh + (size_t)bh * SEQ * HDIM;
  const bf16* vg = vt + (size_t)bh * HDIM * SEQ;

  // Staging geometry (per wave, per tile): 4 K-segments + 4 V-segments,
  // segment index s = w*4 + i.
  // K seg s: rows s*8+(l>>3), phys chunk l&7  <- global chunk (l&7)^(row&7).
  // V seg s: rows s*4+(l>>4), phys chunk l&15 <- global chunk (l&15)^(row&15).
  const bf16* kseg[4];
  const bf16* vseg[4];
#pragma unroll
  for (int i = 0; i < 4; i++) {
    int s = w * 4 + i;
    int krow = s * 8 + (l >> 3);
    kseg[i] = kg + (size_t)krow * HDIM + (((l & 7) ^ (l >> 3)) * 8);
    int vrow = s * 4 + (l >> 4);
    vseg[i] = vg + (size_t)vrow * SEQ + (((l & 15) ^ (vrow & 15)) * 8);
  }

  // Q B-frags (K=32) for the wave's 32 q-rows: q = qt0 + w*32 + g*16 + lr.
  bf16x8 qf[2][2];
#pragma unroll
  for (int g = 0; g < 2; g++)
#pragma unroll
    for (int ko = 0; ko < 2; ko++)
      qf[g][ko] = *(const bf16x8*)(qg + (size_t)(qt0 + w * 32 + g * 16 + lr) * HDIM
                                   + ko * 32 + quad * 8);

  const floatx4 zz = {0.f, 0.f, 0.f, 0.f};
  floatx4 Oacc[2][4];   // [g] O^T[d = dt*16 + quad*4 + r][q = lr]
#pragma unroll
  for (int g = 0; g < 2; g++)
#pragma unroll
    for (int dt = 0; dt < 4; dt++) Oacc[g][dt] = zz;
  float mrow[2] = {-3.0e38f, -3.0e38f};
  float lrow[2] = {0.f, 0.f};

  auto stage = [&](int buf, int kt) {
    bf16* Kb = (bf16*)(smem + buf * 32768);
    bf16* Vb = (bf16*)(smem + buf * 32768 + 16384);
    int off = kt * 128;
#pragma unroll
    for (int i = 0; i < 4; i++) {
      async_cp16(kseg[i] + (size_t)off * HDIM, Kb + (w * 4 + i) * 512);
      async_cp16(vseg[i] + off,                Vb + (w * 4 + i) * 512);
    }
  };

  // prologue: stage tile 0 into buffer 0
  stage(0, 0);

  for (int kt = 0; kt < 16; kt++) {
    const int p = kt & 1;
    __syncthreads();   // drains vmcnt -> tile kt resident in buf p;
                       // all waves done reading buf 1-p (tile kt-1)
    if (kt + 1 < 16) stage(1 - p, kt + 1);
    const bf16* Ks  = (const bf16*)(smem + p * 32768);
    const bf16* Vts = (const bf16*)(smem + p * 32768 + 16384);

    // K A-frag bases are lane-constant; per-ni reads use immediate offsets.
    const bf16* krow0 = Ks + lr * 64 + ((quad ^ (lr & 7)) * 8);
    const bf16* krow1 = Ks + lr * 64 + (((quad + 4) ^ (lr & 7)) * 8);

    // S^T per group: lane holds S[q=lr][key = ni*16 + quad*4 + r], ni=0..7.
    // Each K-frag pair (k0,k1) is read ONCE and feeds both groups.
    floatx4 s0[8], s1[8];
#pragma unroll
    for (int ni = 0; ni < 8; ni++) {
      bf16x8 k0 = *(const bf16x8*)(krow0 + ni * 1024);
      bf16x8 k1 = *(const bf16x8*)(krow1 + ni * 1024);
      floatx4 a0 = MFMA16(k0, qf[0][0], zz);
      floatx4 a1 = MFMA16(k0, qf[1][0], zz);
      a0 = MFMA16(k1, qf[0][1], a0);
      a1 = MFMA16(k1, qf[1][1], a1);
      s0[ni] = a0;
      s1[ni] = a1;
    }

    // ---- Softmax: per-group sequential (R8 order), tree reductions. ----
    bf16x4 pk0[8], pk1[8];
#pragma unroll
    for (int g = 0; g < 2; g++) {
      floatx4* sg = g ? s1 : s0;
      bf16x4* pkg = g ? pk1 : pk0;

      // rmax: per-ni 4-way trees then 8-way tree (depth ~5, was 31-chain)
      float xm[8];
#pragma unroll
      for (int ni = 0; ni < 8; ni++)
        xm[ni] = fmaxf(fmaxf(sg[ni][0], sg[ni][1]), fmaxf(sg[ni][2], sg[ni][3]));
      float rmax = fmaxf(fmaxf(fmaxf(xm[0], xm[1]), fmaxf(xm[2], xm[3])),
                         fmaxf(fmaxf(xm[4], xm[5]), fmaxf(xm[6], xm[7])));
      rmax = fmaxf(rmax, __shfl_xor(rmax, 16, 64));
      rmax = fmaxf(rmax, __shfl_xor(rmax, 32, 64));

      // defer-max (THR=8, exp2 domain): skip O/l rescale when no lane's max
      // grew by more than 8; P then bounded by 2^8, fp32 accum absorbs it.
      if (!__all(rmax - mrow[g] <= 8.0f)) {
        float mnew = fmaxf(mrow[g], rmax);
        float al = fexp2(mrow[g] - mnew);
        mrow[g] = mnew;
        lrow[g] *= al;
#pragma unroll
        for (int dt = 0; dt < 4; dt++)
#pragma unroll
          for (int r = 0; r < 4; r++) Oacc[g][dt][r] *= al;
      }

      // P = exp2(S - m), bf16 pack, pairwise-tree row sum (was 32-chain).
      const float m = mrow[g];
      float tt[8];
#pragma unroll
      for (int ni = 0; ni < 8; ni++) {
        float p0 = fexp2(sg[ni][0] - m), p1 = fexp2(sg[ni][1] - m);
        float p2 = fexp2(sg[ni][2] - m), p3 = fexp2(sg[ni][3] - m);
        pkg[ni][0] = (bf16)p0; pkg[ni][1] = (bf16)p1;
        pkg[ni][2] = (bf16)p2; pkg[ni][3] = (bf16)p3;
        tt[ni] = (p0 + p1) + (p2 + p3);
      }
      float rsum = ((tt[0] + tt[1]) + (tt[2] + tt[3]))
                 + ((tt[4] + tt[5]) + (tt[6] + tt[7]));
      rsum += __shfl_xor(rsum, 16, 64);
      rsum += __shfl_xor(rsum, 32, 64);
      lrow[g] += rsum;
    }

    // PV: O^T += MFMA_16x16x16(Vt_frag, P_frag); each V-frag read feeds
    // both groups. V logical key-offset ni*16+quad*4 -> chunk
    // c=ni*2+(quad>>1), sub=(quad&1)*4; physical chunk = c ^ lr
    // (V row = dt*16+lr, row&15 == lr).
    const bf16* vbase = Vts + lr * 128 + (quad & 1) * 4;
#pragma unroll
    for (int ni = 0; ni < 8; ni++) {
      const bf16* vp = vbase + (((ni * 2 + (quad >> 1)) ^ lr) * 8);
      bf16x4 vf0 = *(const bf16x4*)(vp);
      bf16x4 vf1 = *(const bf16x4*)(vp + 2048);
      bf16x4 vf2 = *(const bf16x4*)(vp + 4096);
      bf16x4 vf3 = *(const bf16x4*)(vp + 6144);
      Oacc[0][0] = MFMA16B(vf0, pk0[ni], Oacc[0][0]);
      Oacc[1][0] = MFMA16B(vf0, pk1[ni], Oacc[1][0]);
      Oacc[0][1] = MFMA16B(vf1, pk0[ni], Oacc[0][1]);
      Oacc[1][1] = MFMA16B(vf1, pk1[ni], Oacc[1][1]);
      Oacc[0][2] = MFMA16B(vf2, pk0[ni], Oacc[0][2]);
      Oacc[1][2] = MFMA16B(vf2, pk1[ni], Oacc[1][2]);
      Oacc[0][3] = MFMA16B(vf3, pk0[ni], Oacc[0][3]);
      Oacc[1][3] = MFMA16B(vf3, pk1[ni], Oacc[1][3]);
    }
  }

  // ---- Epilogue: normalize, transpose via LDS, coalesced store. ----
  // Buffer 0 was last read at tile 14; all waves are past the tile-15
  // barrier, so it is free for the Ost overlay ([128][72] padded, 18KB).
  bf16* Ost = (bf16*)smem;
#pragma unroll
  for (int g = 0; g < 2; g++) {
    float inv = 1.0f / lrow[g];
#pragma unroll
    for (int dt = 0; dt < 4; dt++) {
      bf16x4 ov;
#pragma unroll
      for (int r = 0; r < 4; r++) ov[r] = (bf16)(Oacc[g][dt][r] * inv);
      *(bf16x4*)(Ost + (size_t)(w * 32 + g * 16 + lr) * 72 + dt * 16 + quad * 4) = ov;
    }
  }
  __syncthreads();

  // stream Ost [128 q][64 d] to attn[b][qt0+row][h*64 + d], coalesced 16B.
  const int b = bh >> 4, h = bh & 15;
#pragma unroll
  for (int i = 0; i < 4; i++) {
    int c = t + 256 * i;
    int row = c >> 3, ci = c & 7;
    *(int4*)(attn + ((size_t)b * SEQ + qt0 + row) * D_MODEL + h * HDIM + ci * 8) =
        *(const int4*)(Ost + row * 72 + ci * 8);
  }
}

// ---------------------------------------------------------------------------
// Output projection: out = attn @ Wo^T + bo, fp32 output.
// 128x64 tiles, single-buffered (R10 structure). attn input is bf16 via
// async_cp16; Wo is fp32, reg-staged with inline conversion (2 float4 ->
// 2 bf16x4 ds_writes per thread per K-step). Grid (32,16) = 512 blocks.
// ---------------------------------------------------------------------------
__global__ __launch_bounds__(256) void oproj_gemm(
    const bf16* __restrict__ attn, const float* __restrict__ wo,
    const float* __restrict__ bo, float* __restrict__ out)
{
  __shared__ bf16 As[128 * 32];   // 8KB
  __shared__ bf16 Bs[64 * 32];    // 4KB
  const int m0 = blockIdx.x * 128, n0 = blockIdx.y * 64;
  const int t = threadIdx.x, l = t & 63, w = t >> 6;
  const int quad = l >> 4, lr = l & 15;
  const int wm = (w >> 1) * 64, wn = (w & 1) * 32;
  const int srow = t >> 3, sci = t & 7;

  floatx4 z = {0.f, 0.f, 0.f, 0.f};
  floatx4 acc[4][2];
#pragma unroll
  for (int i = 0; i < 4; i++)
#pragma unroll
    for (int j = 0; j < 2; j++) acc[i][j] = z;

  for (int kt = 0; kt < 1024; kt += 32) {
    __syncthreads();
#pragma unroll
    for (int i = 0; i < 2; i++) {
      int c = i * 256 + t;
      int row = c >> 2, ci = c & 3;          // A: 128 rows x 4 chunks (bf16)
      async_cp16(attn + (size_t)(m0 + row) * 1024 + kt + ci * 8,
                 As + (i * 256 + w * 64) * 8);
    }
#pragma unroll
    for (int jj = 0; jj < 2; jj++) {         // B: 64 rows, fp32 -> bf16
      int row = jj * 32 + srow;
      float4 fw = *(const float4*)(wo + (size_t)(n0 + row) * 1024 + kt + sci * 4);
      *(bf16x4*)(Bs + row * 32 + sci * 4) = cvt4(fw);
    }
    __syncthreads();

    bf16x8 af[4], bfr[2];
#pragma unroll
    for (int i = 0; i < 4; i++)
      af[i]  = *(const bf16x8*)(As + (wm + i * 16 + lr) * 32 + quad * 8);
#pragma unroll
    for (int j = 0; j < 2; j++)
      bfr[j] = *(const bf16x8*)(Bs + (wn + j * 16 + lr) * 32 + quad * 8);
#pragma unroll
    for (int i = 0; i < 4; i++)
#pragma unroll
      for (int j = 0; j < 2; j++)
        acc[i][j] = MFMA16(af[i], bfr[j], acc[i][j]);
  }

#pragma unroll
  for (int i = 0; i < 4; i++) {
    int m = m0 + wm + i * 16 + quad * 4;
#pragma unroll
    for (int j = 0; j < 2; j++) {
      int n = n0 + wn + j * 16 + lr;
      float bv = bo[n];
      float* p = out + (size_t)m * D_MODEL + n;
#pragma unroll
      for (int r = 0; r < 4; r++)
        p[(size_t)r * D_MODEL] = acc[i][j][r] + bv;
    }
  }
}

// ---------------------------------------------------------------------------
extern "C" void kernel_launch(void* const* d_in, const int* in_sizes, int n_in,
                              void* d_out, int out_size, void* d_ws, size_t ws_size,
                              hipStream_t stream)
{
  const float* q  = (const float*)d_in[0];
  const float* k  = (const float*)d_in[1];
  const float* v  = (const float*)d_in[2];
  const float* Wq = (const float*)d_in[3];
  const float* bq = (const float*)d_in[4];
  const float* Wk = (const float*)d_in[5];
  const float* bk = (const float*)d_in[6];
  const float* Wv = (const float*)d_in[7];
  const float* bv = (const float*)d_in[8];
  const float* Wo = (const float*)d_in[9];
  const float* bo = (const float*)d_in[10];

  const size_t NQ = (size_t)BT * D_MODEL;        // 4194304

  bf16* p = (bf16*)d_ws;
  bf16* qhp  = p; p += NQ;   // [B*H][T][64], pre-scaled by QSCALE
  bf16* khp  = p; p += NQ;   // [B*H][T][64]
  bf16* vtp  = p; p += NQ;   // [B*H][64][T]
  bf16* attn = p; p += NQ;   // [B][T][1024]

  qkv_gemm<<<dim3(32, 8, 3), 256, 0, stream>>>(q, k, v, Wq, Wk, Wv,
                                               bq, bk, bv, qhp, khp, vtp);
  attn_fused<<<dim3(16, 32, 1), 256, 0, stream>>>(qhp, khp, vtp, attn);
  oproj_gemm<<<dim3(32, 16, 1), 256, 0, stream>>>(attn, Wo, bo, (float*)d_out);
}

// Round 6
// 215.521 us; speedup vs baseline: 1.1265x; 1.1265x over previous
//
#include <hip/hip_runtime.h>
#include <cstdint>
#include <cstddef>

// ---------------------------------------------------------------------------
// MultiHeadAttention forward, MI355X/gfx950.
// cvt(fp32->bf16) -> fused QKV GEMM (MFMA) -> flash attention -> out-proj.
// MFMA layouts (m89/m91/m120):
//   K=32 A-frag: lane l holds A[m=l&15][k=(l>>4)*8+j], j=0..7
//   K=32 B-frag: lane l holds Bt[n=l&15][k=(l>>4)*8+j]
//   K=16 A/B-frag: lane l holds X[.=l&15][k=(l>>4)*4+c], c=0..3
//   C/D: lane l, reg r holds D[m=(l>>4)*4+r][n=l&15]
// R13: revert pipeline to R10 (224.8us best; R11 dbuf +9, R12 cvt-fusion +18
// both falsified -- R12's counters showed qkv FETCH 74-95MB: fp32 re-reads
// of A(x8)/W(x32) overflow L2; separate one-pass cvt7 keeps GEMM re-reads
// bf16 + cache-resident). attn changes only (VALU 50% > MFMA 33%):
//  * lrow via MFMA ones-trick: rowsum(P) accumulated by an extra
//    MFMA(ones, P) per P-fragment into Racc (all 16 output rows = the sum;
//    read reg0). Removes the per-tile VALU add-tree + 2 shfl_xor (~35 ops/
//    group/tile) and moves the work to the less-busy MFMA pipe. Rescale
//    scales Racc like Oacc. Also more consistent: sums the bf16 P that PV
//    actually uses.
//  * PV at K=32: MFMA contracts over an agreed k-slot order, so pairing two
//    ni-fragments (concat(pk[2n],pk[2n+1]) vs concat(vfA,vfB)) gives
//    16x16x32 PV: 32 K=16 MFMAs -> 16 K=32 MFMAs. Same FLOPs, half the
//    instructions and accumulate-chain depth.
//  * rmax tree in max3-fusable form (31 -> ~20 ops/group).
// Kept: 4 waves x 32 q (2 groups of 16) sharing every K/V LDS read, XCD
// swizzle (FETCH 69.7->12.4MB), XOR-swizzled unpadded K/V LDS,
// global_load_lds double-buffered staging with ONE barrier per tile,
// defer-max (THR=8), exp2 domain (QSCALE folded into Q projection),
// no setprio, oproj 128x64 single-buffered.
// ---------------------------------------------------------------------------

#define D_MODEL 1024
#define NHEAD   16
#define HDIM    64
#define BATCH   2
#define SEQ     2048
#define BT      (BATCH * SEQ)   // 4096

// (1/sqrt(HDIM)) * log2(e) -- folds softmax scale + exp->exp2 conversion
#define QSCALE 0.18033688011112043f

typedef __bf16 bf16;
typedef __bf16 bf16x8 __attribute__((ext_vector_type(8)));
typedef __bf16 bf16x4 __attribute__((ext_vector_type(4)));
typedef float  floatx4 __attribute__((ext_vector_type(4)));
typedef short  short4v __attribute__((ext_vector_type(4)));

#define MFMA16(a, b, c) __builtin_amdgcn_mfma_f32_16x16x32_bf16((a), (b), (c), 0, 0, 0)

__device__ __forceinline__ float fexp2(float x) {
  return __builtin_amdgcn_exp2f(x);   // v_exp_f32: D = 2^S0
}

// async global->LDS, 16B per lane. LDS dest = wave-uniform base + lane*16.
__device__ __forceinline__ void async_cp16(const bf16* g, bf16* l) {
  __builtin_amdgcn_global_load_lds(
      (__attribute__((address_space(1))) void*)(g),
      (__attribute__((address_space(3))) void*)(l), 16, 0, 0);
}

// ---------------------------------------------------------------------------
// fp32 -> bf16 conversion for q,k,v and the 4 weight matrices.
// ---------------------------------------------------------------------------
__global__ __launch_bounds__(256) void cvt7(
    const float* __restrict__ s0, const float* __restrict__ s1,
    const float* __restrict__ s2, const float* __restrict__ s3,
    const float* __restrict__ s4, const float* __restrict__ s5,
    const float* __restrict__ s6,
    bf16* __restrict__ d0, bf16* __restrict__ d1, bf16* __restrict__ d2,
    bf16* __restrict__ d3, bf16* __restrict__ d4, bf16* __restrict__ d5,
    bf16* __restrict__ d6)
{
  const float* src; bf16* dst; int n4;
  switch (blockIdx.y) {
    case 0:  src = s0; dst = d0; n4 = (BT * D_MODEL) / 4; break;
    case 1:  src = s1; dst = d1; n4 = (BT * D_MODEL) / 4; break;
    case 2:  src = s2; dst = d2; n4 = (BT * D_MODEL) / 4; break;
    case 3:  src = s3; dst = d3; n4 = (D_MODEL * D_MODEL) / 4; break;
    case 4:  src = s4; dst = d4; n4 = (D_MODEL * D_MODEL) / 4; break;
    case 5:  src = s5; dst = d5; n4 = (D_MODEL * D_MODEL) / 4; break;
    default: src = s6; dst = d6; n4 = (D_MODEL * D_MODEL) / 4; break;
  }
  int stride = gridDim.x * blockDim.x;
  for (int i = blockIdx.x * blockDim.x + threadIdx.x; i < n4; i += stride) {
    float4 f = ((const float4*)src)[i];
    bf16x4 h;
    h[0] = (bf16)f.x; h[1] = (bf16)f.y; h[2] = (bf16)f.z; h[3] = (bf16)f.w;
    ((bf16x4*)dst)[i] = h;
  }
}

// ---------------------------------------------------------------------------
// 128x128-tile GEMM core, K=1024, BK=32 (m97 structure, single-buffered:
// TLP across 3 blocks/CU hides staging latency; explicit dbuf regressed R11).
// ---------------------------------------------------------------------------
__device__ __forceinline__ void gemm128_core(
    const bf16* __restrict__ A, const bf16* __restrict__ W,
    int m0, int n0, bf16* As, bf16* Bs, floatx4 acc[4][4])
{
  const int t = threadIdx.x;
  const int l = t & 63, w = t >> 6;
  const int quad = l >> 4, lr = l & 15;
  const int wm = (w >> 1) * 64, wn = (w & 1) * 64;

  floatx4 z = {0.f, 0.f, 0.f, 0.f};
#pragma unroll
  for (int i = 0; i < 4; i++)
#pragma unroll
    for (int j = 0; j < 4; j++) acc[i][j] = z;

  for (int kt = 0; kt < 1024; kt += 32) {
    __syncthreads();
#pragma unroll
    for (int i = 0; i < 2; i++) {
      int c = i * 256 + t;
      int row = c >> 2, ci = c & 3;
      async_cp16(A + (size_t)(m0 + row) * 1024 + kt + ci * 8,
                 As + (i * 256 + w * 64) * 8);
      async_cp16(W + (size_t)(n0 + row) * 1024 + kt + ci * 8,
                 Bs + (i * 256 + w * 64) * 8);
    }
    __syncthreads();

    bf16x8 af[4], bfr[4];
#pragma unroll
    for (int i = 0; i < 4; i++) {
      af[i]  = *(const bf16x8*)(As + (wm + i * 16 + lr) * 32 + quad * 8);
      bfr[i] = *(const bf16x8*)(Bs + (wn + i * 16 + lr) * 32 + quad * 8);
    }
#pragma unroll
    for (int i = 0; i < 4; i++)
#pragma unroll
      for (int j = 0; j < 4; j++)
        acc[i][j] = MFMA16(af[i], bfr[j], acc[i][j]);
  }
}

// ---------------------------------------------------------------------------
// Fused QKV projection. zid selects (q,Wq)->qh, (k,Wk)->kh, (v,Wv)->vt.
// qh,kh: [B*H][T][64]; v stored TRANSPOSED [B*H][64][T].
// qh is pre-scaled by QSCALE (softmax scale folded + exp2 domain).
// ---------------------------------------------------------------------------
__global__ __launch_bounds__(256) void qkv_gemm(
    const bf16* __restrict__ qb, const bf16* __restrict__ kb, const bf16* __restrict__ vb,
    const bf16* __restrict__ wq, const bf16* __restrict__ wk, const bf16* __restrict__ wv,
    const float* __restrict__ biasq, const float* __restrict__ biask, const float* __restrict__ biasv,
    bf16* __restrict__ qh, bf16* __restrict__ kh, bf16* __restrict__ vt)
{
  __shared__ bf16 As[128 * 32];
  __shared__ bf16 Bs[128 * 32];
  const int zid = blockIdx.z;
  const bf16* A = (zid == 0) ? qb : ((zid == 1) ? kb : vb);
  const bf16* W = (zid == 0) ? wq : ((zid == 1) ? wk : wv);
  const float* bias = (zid == 0) ? biasq : ((zid == 1) ? biask : biasv);
  const int m0 = blockIdx.x * 128, n0 = blockIdx.y * 128;

  floatx4 acc[4][4];
  gemm128_core(A, W, m0, n0, As, Bs, acc);

  const int t = threadIdx.x, l = t & 63, w = t >> 6;
  const int quad = l >> 4, lr = l & 15;
  const int wm = (w >> 1) * 64, wn = (w & 1) * 64;
  const float sc = (zid == 0) ? QSCALE : 1.0f;

  if (zid < 2) {
    bf16* out = (zid == 0) ? qh : kh;
#pragma unroll
    for (int i = 0; i < 4; i++) {
      int mbase = m0 + wm + i * 16 + quad * 4;       // global row (b*2048+t)
      int b  = mbase >> 11;
      int tq = mbase & 2047;
#pragma unroll
      for (int j = 0; j < 4; j++) {
        int n = n0 + wn + j * 16 + lr;               // e = h*64 + dh
        float bv = bias[n];
        int h = n >> 6, dh = n & 63;
        bf16* p = out + ((size_t)((b * NHEAD + h) * SEQ + tq)) * HDIM + dh;
#pragma unroll
        for (int r = 0; r < 4; r++)
          p[(size_t)r * HDIM] = (bf16)((acc[i][j][r] + bv) * sc);
      }
    }
  } else {
#pragma unroll
    for (int i = 0; i < 4; i++) {
      int mbase = m0 + wm + i * 16 + quad * 4;
      int b  = mbase >> 11;
      int tq = mbase & 2047;
#pragma unroll
      for (int j = 0; j < 4; j++) {
        int n = n0 + wn + j * 16 + lr;
        float bv = bias[n];
        int h = n >> 6, dh = n & 63;
        bf16x4 pk;
#pragma unroll
        for (int r = 0; r < 4; r++) pk[r] = (bf16)(acc[i][j][r] + bv);
        *(bf16x4*)(vt + ((size_t)((b * NHEAD + h) * HDIM + dh)) * SEQ + tq) = pk;
      }
    }
  }
}

// ---------------------------------------------------------------------------
// Flash attention. Grid (T/128, B*H), block 256 = 4 waves; wave w owns
// q-rows qt0 + w*32 + {0..31} as TWO groups of 16 (g=0,1; q = g*16 + lr),
// all 128 keys of each tile. Every K-frag / V-frag LDS read feeds BOTH
// groups' MFMAs. Block ids are XCD-swizzled so the 16 q-tile blocks of a
// given bh (+3 more bh) share one XCD's L2 (K/V working set 3MB < 4MB).
// LDS (double-buffered, 2 x 32 KB):
//   K  [128 rows][64 el],  8-el chunk ci stored at physical ci ^ (row & 7)
//   V^T[ 64 rows][128 el], 8-el chunk ci stored at physical ci ^ (row & 15)
// Staged via global_load_lds: 4 waves x (4 K-seg + 4 V-seg) x 1 KB per tile;
// one barrier per tile (issue DMA for tile k+1 right after barrier k).
// Compute: S^T = MFMA16x16x32(K,Q) per group; max3-tree exp2 softmax with
// defer-max skip; PV via K=32 MFMA over paired ni-fragments; row-sum P via
// ones-MFMA into Racc (replaces VALU add-tree + shfl).
// Epilogue: normalize by Racc[0], LDS transpose ([128][72] overlay),
// coalesced store.
// ---------------------------------------------------------------------------
__global__ __launch_bounds__(256, 2) void attn_fused(
    const bf16* __restrict__ qh, const bf16* __restrict__ kh,
    const bf16* __restrict__ vt, bf16* __restrict__ attn)
{
  __shared__ __align__(16) char smem[65536];   // 2 x (K 16KB + V 16KB)

  const int t = threadIdx.x, l = t & 63, w = t >> 6;   // w in 0..3
  const int quad = l >> 4, lr = l & 15;

  // XCD swizzle: hardware dispatch round-robins linear block id across the
  // 8 XCDs (id % 8 = XCD). Give XCD x the 4 heads {x, x+8, x+16, x+24},
  // all 16 q-tiles each: bijective over the 512-block grid.
  const int hb  = blockIdx.y * 16 + blockIdx.x;   // dispatch-linear id
  const int j   = hb >> 3;
  const int bh  = (hb & 7) + ((j & 3) << 3);
  const int qt0 = (j >> 2) * 128;

  const bf16* qg = qh + (size_t)bh * SEQ * HDIM;
  const bf16* kg = kh + (size_t)bh * SEQ * HDIM;
  const bf16* vg = vt + (size_t)bh * HDIM * SEQ;

  // Staging geometry (per wave, per tile): 4 K-segments + 4 V-segments,
  // segment index s = w*4 + i.
  // K seg s: rows s*8+(l>>3), phys chunk l&7  <- global chunk (l&7)^(row&7).
  // V seg s: rows s*4+(l>>4), phys chunk l&15 <- global chunk (l&15)^(row&15).
  const bf16* kseg[4];
  const bf16* vseg[4];
#pragma unroll
  for (int i = 0; i < 4; i++) {
    int s = w * 4 + i;
    int krow = s * 8 + (l >> 3);
    kseg[i] = kg + (size_t)krow * HDIM + (((l & 7) ^ (l >> 3)) * 8);
    int vrow = s * 4 + (l >> 4);
    vseg[i] = vg + (size_t)vrow * SEQ + (((l & 15) ^ (vrow & 15)) * 8);
  }

  // Q B-frags (K=32) for the wave's 32 q-rows: q = qt0 + w*32 + g*16 + lr.
  bf16x8 qf[2][2];
#pragma unroll
  for (int g = 0; g < 2; g++)
#pragma unroll
    for (int ko = 0; ko < 2; ko++)
      qf[g][ko] = *(const bf16x8*)(qg + (size_t)(qt0 + w * 32 + g * 16 + lr) * HDIM
                                   + ko * 32 + quad * 8);

  const floatx4 zz = {0.f, 0.f, 0.f, 0.f};
  floatx4 Oacc[2][4];   // [g] O^T[d = dt*16 + quad*4 + r][q = lr]
#pragma unroll
  for (int g = 0; g < 2; g++)
#pragma unroll
    for (int dt = 0; dt < 4; dt++) Oacc[g][dt] = zz;
  floatx4 Racc[2] = {zz, zz};   // rowsum(P) accum; all regs equal the sum
  float mrow[2] = {-3.0e38f, -3.0e38f};

  bf16x8 ones8;
#pragma unroll
  for (int i = 0; i < 8; i++) ones8[i] = (bf16)1.0f;

  auto stage = [&](int buf, int kt) {
    bf16* Kb = (bf16*)(smem + buf * 32768);
    bf16* Vb = (bf16*)(smem + buf * 32768 + 16384);
    int off = kt * 128;
#pragma unroll
    for (int i = 0; i < 4; i++) {
      async_cp16(kseg[i] + (size_t)off * HDIM, Kb + (w * 4 + i) * 512);
      async_cp16(vseg[i] + off,                Vb + (w * 4 + i) * 512);
    }
  };

  // prologue: stage tile 0 into buffer 0
  stage(0, 0);

  for (int kt = 0; kt < 16; kt++) {
    const int p = kt & 1;
    __syncthreads();   // drains vmcnt -> tile kt resident in buf p;
                       // all waves done reading buf 1-p (tile kt-1)
    if (kt + 1 < 16) stage(1 - p, kt + 1);
    const bf16* Ks  = (const bf16*)(smem + p * 32768);
    const bf16* Vts = (const bf16*)(smem + p * 32768 + 16384);

    // K A-frag bases are lane-constant; per-ni reads use immediate offsets.
    const bf16* krow0 = Ks + lr * 64 + ((quad ^ (lr & 7)) * 8);
    const bf16* krow1 = Ks + lr * 64 + (((quad + 4) ^ (lr & 7)) * 8);

    // S^T per group: lane holds S[q=lr][key = ni*16 + quad*4 + r], ni=0..7.
    // Each K-frag pair (k0,k1) is read ONCE and feeds both groups.
    floatx4 s0[8], s1[8];
#pragma unroll
    for (int ni = 0; ni < 8; ni++) {
      bf16x8 k0 = *(const bf16x8*)(krow0 + ni * 1024);
      bf16x8 k1 = *(const bf16x8*)(krow1 + ni * 1024);
      floatx4 a0 = MFMA16(k0, qf[0][0], zz);
      floatx4 a1 = MFMA16(k0, qf[1][0], zz);
      a0 = MFMA16(k1, qf[0][1], a0);
      a1 = MFMA16(k1, qf[1][1], a1);
      s0[ni] = a0;
      s1[ni] = a1;
    }

    // ---- Softmax: per-group, max3-tree rmax, defer-max, exp2+pack. ----
    // pk layout for K=32 PV: pkg[nip][0..3] = P keys (2nip)*16+quad*4+r,
    //                        pkg[nip][4..7] = P keys (2nip+1)*16+quad*4+r.
    bf16x8 pk0[4], pk1[4];
#pragma unroll
    for (int g = 0; g < 2; g++) {
      floatx4* sg = g ? s1 : s0;
      bf16x8* pkg = g ? pk1 : pk0;

      float xm[8];
#pragma unroll
      for (int ni = 0; ni < 8; ni++) {
        float m01 = fmaxf(sg[ni][0], sg[ni][1]);
        xm[ni] = fmaxf(fmaxf(m01, sg[ni][2]), sg[ni][3]);   // max3-fusable
      }
      float rmax = fmaxf(fmaxf(xm[0], xm[1]), xm[2]);
      rmax = fmaxf(fmaxf(rmax, xm[3]), xm[4]);
      rmax = fmaxf(fmaxf(rmax, xm[5]), xm[6]);
      rmax = fmaxf(rmax, xm[7]);
      rmax = fmaxf(rmax, __shfl_xor(rmax, 16, 64));
      rmax = fmaxf(rmax, __shfl_xor(rmax, 32, 64));

      // defer-max (THR=8, exp2 domain): skip O/R rescale when no lane's max
      // grew by more than 8; P then bounded by 2^8, fp32 accum absorbs it.
      if (!__all(rmax - mrow[g] <= 8.0f)) {
        float mnew = fmaxf(mrow[g], rmax);
        float al = fexp2(mrow[g] - mnew);
        mrow[g] = mnew;
#pragma unroll
        for (int dt = 0; dt < 4; dt++)
#pragma unroll
          for (int r = 0; r < 4; r++) Oacc[g][dt][r] *= al;
#pragma unroll
        for (int r = 0; r < 4; r++) Racc[g][r] *= al;
      }

      const float m = mrow[g];
#pragma unroll
      for (int nip = 0; nip < 4; nip++) {
        bf16x8 pv;
#pragma unroll
        for (int r = 0; r < 4; r++) pv[r]     = (bf16)fexp2(sg[2*nip  ][r] - m);
#pragma unroll
        for (int r = 0; r < 4; r++) pv[4 + r] = (bf16)fexp2(sg[2*nip+1][r] - m);
        pkg[nip] = pv;
      }
    }

    // PV at K=32: k-slot (quad,j) -> key ni(j)*16 + quad*4 + (j&3), with
    // ni(j) = 2nip + (j>=4). A-frag = concat of the two bf16x4 V chunks
    // (logical chunk 4nip+(quad>>1) and 4nip+2+(quad>>1), phys = c ^ lr,
    // sub-offset (quad&1)*4); B-frag = pkg[nip]. Both sides use the same
    // slot order, so the contraction is exact. Racc accumulates rowsum(P)
    // via an A=ones MFMA (every output row = the sum).
    const bf16* vbase = Vts + lr * 128 + (quad & 1) * 4;
#pragma unroll
    for (int nip = 0; nip < 4; nip++) {
      const bf16* vpA = vbase + ((((4 * nip)     + (quad >> 1)) ^ lr) * 8);
      const bf16* vpB = vbase + ((((4 * nip + 2) + (quad >> 1)) ^ lr) * 8);
      Racc[0] = MFMA16(ones8, pk0[nip], Racc[0]);
      Racc[1] = MFMA16(ones8, pk1[nip], Racc[1]);
#pragma unroll
      for (int dt = 0; dt < 4; dt++) {
        bf16x4 va = *(const bf16x4*)(vpA + dt * 2048);
        bf16x4 vb = *(const bf16x4*)(vpB + dt * 2048);
        bf16x8 vf8 = __builtin_shufflevector(va, vb, 0, 1, 2, 3, 4, 5, 6, 7);
        Oacc[0][dt] = MFMA16(vf8, pk0[nip], Oacc[0][dt]);
        Oacc[1][dt] = MFMA16(vf8, pk1[nip], Oacc[1][dt]);
      }
    }
  }

  // ---- Epilogue: normalize, transpose via LDS, coalesced store. ----
  // Buffer 0 was last read at tile 14; all waves are past the tile-15
  // barrier, so it is free for the Ost overlay ([128][72] padded, 18KB).
  bf16* Ost = (bf16*)smem;
#pragma unroll
  for (int g = 0; g < 2; g++) {
    float inv = 1.0f / Racc[g][0];
#pragma unroll
    for (int dt = 0; dt < 4; dt++) {
      bf16x4 ov;
#pragma unroll
      for (int r = 0; r < 4; r++) ov[r] = (bf16)(Oacc[g][dt][r] * inv);
      *(bf16x4*)(Ost + (size_t)(w * 32 + g * 16 + lr) * 72 + dt * 16 + quad * 4) = ov;
    }
  }
  __syncthreads();

  // stream Ost [128 q][64 d] to attn[b][qt0+row][h*64 + d], coalesced 16B.
  const int b = bh >> 4, h = bh & 15;
#pragma unroll
  for (int i = 0; i < 4; i++) {
    int c = t + 256 * i;
    int row = c >> 3, ci = c & 7;
    *(int4*)(attn + ((size_t)b * SEQ + qt0 + row) * D_MODEL + h * HDIM + ci * 8) =
        *(const int4*)(Ost + row * 72 + ci * 8);
  }
}

// ---------------------------------------------------------------------------
// Output projection: out = attn @ Wo^T + bo, fp32 output.
// 128x64 tiles, single-buffered (R10 structure). Grid (32,16) = 512 blocks.
// ---------------------------------------------------------------------------
__global__ __launch_bounds__(256) void oproj_gemm(
    const bf16* __restrict__ attn, const bf16* __restrict__ wo,
    const float* __restrict__ bo, float* __restrict__ out)
{
  __shared__ bf16 As[128 * 32];   // 8KB
  __shared__ bf16 Bs[64 * 32];    // 4KB
  const int m0 = blockIdx.x * 128, n0 = blockIdx.y * 64;
  const int t = threadIdx.x, l = t & 63, w = t >> 6;
  const int quad = l >> 4, lr = l & 15;
  const int wm = (w >> 1) * 64, wn = (w & 1) * 32;

  floatx4 z = {0.f, 0.f, 0.f, 0.f};
  floatx4 acc[4][2];
#pragma unroll
  for (int i = 0; i < 4; i++)
#pragma unroll
    for (int j = 0; j < 2; j++) acc[i][j] = z;

  for (int kt = 0; kt < 1024; kt += 32) {
    __syncthreads();
#pragma unroll
    for (int i = 0; i < 2; i++) {
      int c = i * 256 + t;
      int row = c >> 2, ci = c & 3;          // A: 128 rows x 4 chunks
      async_cp16(attn + (size_t)(m0 + row) * 1024 + kt + ci * 8,
                 As + (i * 256 + w * 64) * 8);
    }
    {
      int row = t >> 2, ci = t & 3;          // B: 64 rows x 4 chunks
      async_cp16(wo + (size_t)(n0 + row) * 1024 + kt + ci * 8,
                 Bs + (w * 64) * 8);
    }
    __syncthreads();

    bf16x8 af[4], bfr[2];
#pragma unroll
    for (int i = 0; i < 4; i++)
      af[i]  = *(const bf16x8*)(As + (wm + i * 16 + lr) * 32 + quad * 8);
#pragma unroll
    for (int j = 0; j < 2; j++)
      bfr[j] = *(const bf16x8*)(Bs + (wn + j * 16 + lr) * 32 + quad * 8);
#pragma unroll
    for (int i = 0; i < 4; i++)
#pragma unroll
      for (int j = 0; j < 2; j++)
        acc[i][j] = MFMA16(af[i], bfr[j], acc[i][j]);
  }

#pragma unroll
  for (int i = 0; i < 4; i++) {
    int m = m0 + wm + i * 16 + quad * 4;
#pragma unroll
    for (int j = 0; j < 2; j++) {
      int n = n0 + wn + j * 16 + lr;
      float bv = bo[n];
      float* p = out + (size_t)m * D_MODEL + n;
#pragma unroll
      for (int r = 0; r < 4; r++)
        p[(size_t)r * D_MODEL] = acc[i][j][r] + bv;
    }
  }
}

// ---------------------------------------------------------------------------
extern "C" void kernel_launch(void* const* d_in, const int* in_sizes, int n_in,
                              void* d_out, int out_size, void* d_ws, size_t ws_size,
                              hipStream_t stream)
{
  const float* q  = (const float*)d_in[0];
  const float* k  = (const float*)d_in[1];
  const float* v  = (const float*)d_in[2];
  const float* Wq = (const float*)d_in[3];
  const float* bq = (const float*)d_in[4];
  const float* Wk = (const float*)d_in[5];
  const float* bk = (const float*)d_in[6];
  const float* Wv = (const float*)d_in[7];
  const float* bv = (const float*)d_in[8];
  const float* Wo = (const float*)d_in[9];
  const float* bo = (const float*)d_in[10];

  const size_t NQ = (size_t)BT * D_MODEL;        // 4194304
  const size_t NW = (size_t)D_MODEL * D_MODEL;   // 1048576

  bf16* p = (bf16*)d_ws;
  bf16* qb   = p; p += NQ;
  bf16* kb   = p; p += NQ;
  bf16* vb   = p; p += NQ;
  bf16* wqb  = p; p += NW;
  bf16* wkb  = p; p += NW;
  bf16* wvb  = p; p += NW;
  bf16* wob  = p; p += NW;
  bf16* qhp  = p; p += NQ;   // [B*H][T][64], pre-scaled by QSCALE
  bf16* khp  = p; p += NQ;   // [B*H][T][64]
  bf16* vtp  = p; p += NQ;   // [B*H][64][T]
  bf16* attn = p; p += NQ;   // [B][T][1024]

  cvt7<<<dim3(1024, 7, 1), 256, 0, stream>>>(q, k, v, Wq, Wk, Wv, Wo,
                                             qb, kb, vb, wqb, wkb, wvb, wob);
  qkv_gemm<<<dim3(32, 8, 3), 256, 0, stream>>>(qb, kb, vb, wqb, wkb, wvb,
                                               bq, bk, bv, qhp, khp, vtp);
  attn_fused<<<dim3(16, 32, 1), 256, 0, stream>>>(qhp, khp, vtp, attn);
  oproj_gemm<<<dim3(32, 16, 1), 256, 0, stream>>>(attn, wob, bo, (float*)d_out);
}